// Round 8
// baseline (611.222 us; speedup 1.0000x reference)
//
#include <hip/hip_runtime.h>
#include <hip/hip_bf16.h>
#include <stdint.h>

// F8Linear: y[m,n] = sum_k x[m,k] * (w_f8[n,k] * s) + bias[n]
// M=1024, N=14336, K=4096.
// R16: OCCUPANCY kernel. R8-R15 cross-evidence: every schedule at 2
//   waves/SIMD lands 184-217 us with all pipes <35% utilized ->
//   latency-bound, not schedule-bound. This round: 128x128 tile, TK=32,
//   256 thr (4 waves, 2Mx2N, 64x64/wave = R8's verified epilogue), dbuf
//   LDS 32 KiB -> 3.5 blocks/CU (14 waves/CU, was 8). Fused f32->bf16 B
//   reg-staging + 1-barrier shell kept. New 4-slot swizzle for 64B rows:
//   phys = g ^ ((row>>1)&3) -> 8 bank-slots hit 2x over 16 lanes (free).
// R15 post-mortem: 32x32 MFMA halved instrs but its 32-row frag read
//   4-way-conflicts the 8-slot swizzle (SQ_LDS_BANK_CONFLICT 0 -> 1.1e7);
//   net wash at 212 us. Reverting to 16x16 core.

#define IN_F   4096
#define OUT_F  14336
#define M_TOT  1024

// legacy fallback tile params
#define BM 128
#define BN 128

// R16 kernel params
#define TM2 128
#define TN2 128
#define TK2 32
#define NT2 (IN_F / TK2)   // 128 K-tiles

typedef __bf16  bf16x8 __attribute__((ext_vector_type(8)));
typedef __bf16  bf16x4 __attribute__((ext_vector_type(4)));
typedef float   f32x4  __attribute__((ext_vector_type(4)));

__device__ __forceinline__ void async_copy16(const void* g, void* l) {
    __builtin_amdgcn_global_load_lds(
        (const __attribute__((address_space(1))) void*)g,
        (__attribute__((address_space(3))) void*)l,
        16, 0, 0);
}

// ---- detector: bf16-valued f32 words have low16 == 0 over 1024 dwords ----
__global__ void detect_x_dtype(const uint32_t* __restrict__ xb,
                               int* __restrict__ flag) {
    __shared__ int any_low;
    if (threadIdx.x == 0) any_low = 0;
    __syncthreads();
    uint32_t bad = 0;
    for (int i = threadIdx.x; i < 1024; i += 256) bad |= (xb[i] & 0xFFFFu);
    if (bad) atomicOr(&any_low, 1);
    __syncthreads();
    if (threadIdx.x == 0) *flag = (any_low == 0) ? 1 : 0;
}

// ---- cvt_x: 4,194,304 elems -> bf16 (cvt f32-world, copy bf16-world) ----
__global__ __launch_bounds__(256) void cvt_x_kernel(
    const void* __restrict__ xraw, bf16x8* __restrict__ out,
    const int* __restrict__ flag) {
    const int f32w = (*flag != 0);
    const int i = blockIdx.x * 256 + threadIdx.x;   // 0..524287
    if (f32w) {
        const f32x4* in = (const f32x4*)xraw;
        f32x4 a = in[2 * i];
        f32x4 b = in[2 * i + 1];
        bf16x8 o;
        o[0] = (__bf16)a[0]; o[1] = (__bf16)a[1];
        o[2] = (__bf16)a[2]; o[3] = (__bf16)a[3];
        o[4] = (__bf16)b[0]; o[5] = (__bf16)b[1];
        o[6] = (__bf16)b[2]; o[7] = (__bf16)b[3];
        out[i] = o;
    } else {
        out[i] = ((const bf16x8*)xraw)[i];
    }
}

// ---- main GEMM: 128x128 tile, TK=32, 4 waves, high occupancy ----
__global__ __launch_bounds__(256, 4) void gemm_fused_occ(
    const __bf16* __restrict__ xb,     // [M_TOT][IN_F] bf16 (ws)
    const float*  __restrict__ wf,     // [OUT_F][IN_F] f32 (original input)
    const float*  __restrict__ w_scale,
    const float*  __restrict__ bias,
    void*         __restrict__ yraw,   // f32 or bf16 container per flag
    const int*    __restrict__ flag_p)
{
    // [dbuf]: 128 rows x 32 cols bf16 = 8 KiB per operand. Total 32 KiB.
    __shared__ __align__(16) __bf16 As[2][128 * TK2];
    __shared__ __align__(16) __bf16 Bs[2][128 * TK2];

    const int f32w = (*flag_p != 0);
    const int t    = threadIdx.x;      // 0..255
    const int lane = t & 63;
    const int wv   = t >> 6;           // 0..3
    const int wm   = wv >> 1;          // 0..1
    const int wn   = wv & 1;           // 0..1
    const int lidx = lane & 15;
    const int q    = lane >> 4;        // 0..3 (k-quarter)

    // XCD map (R8, bijective over 896 = 8 Mtiles x 112 Ntiles):
    // each XCD owns 14 N-panels; the 8 M-tiles of a panel co-reside -> B
    // panel (2 MB f32) is L2-resident per XCD.
    const int flat = blockIdx.x;
    const int xcd  = flat & 7;
    const int slot = flat >> 3;            // 0..111
    const int ni   = xcd * 14 + (slot >> 3);
    const int mi   = slot & 7;
    const int m0   = mi * TM2;
    const int n0   = ni * TN2;

    const float scale = w_scale[0];

    const __bf16* gA = xb + (size_t)m0 * IN_F;

    // staging: buffer = 512 slots of 16B (8 bf16). slot s: row = s>>2,
    // phys 16B-group = s&3 holds LOGICAL group lg = (s&3) ^ ((row>>1)&3)
    // (4-slot swizzle for 64B rows; LDS dest stays linear for gload_lds).
    int srow[2], slg[2];
    #pragma unroll
    for (int i = 0; i < 2; ++i) {
        const int s = i * 256 + t;
        srow[i] = s >> 2;
        slg[i]  = (s & 3) ^ ((srow[i] >> 1) & 3);
    }

    // B source (f32): per-thread bases for the two slots
    const float* gB0 = wf + (size_t)(n0 + srow[0]) * IN_F + slg[0] * 8;
    const float* gB1 = wf + (size_t)(n0 + srow[1]) * IN_F + slg[1] * 8;

    // ds_read byte offsets (row*64B + phys*16B), phys = q ^ ((r>>1)&3).
    int aoff[4], boff[4];
    #pragma unroll
    for (int mt = 0; mt < 4; ++mt) {
        const int r = wm * 64 + mt * 16 + lidx;
        aoff[mt] = r * 64 + ((q ^ ((r >> 1) & 3)) * 16);
    }
    #pragma unroll
    for (int nt = 0; nt < 4; ++nt) {
        const int r = wn * 64 + nt * 16 + lidx;
        boff[nt] = r * 64 + ((q ^ ((r >> 1) & 3)) * 16);
    }

    const f32x4 zero4 = {0.f, 0.f, 0.f, 0.f};
    f32x4 acc[4][4];                   // 64 regs
    #pragma unroll
    for (int i = 0; i < 4; ++i)
        #pragma unroll
        for (int j = 0; j < 4; ++j)
            acc[i][j] = zero4;

    f32x4 Br[4];                       // 16 VGPR B staging (2 slots x 32B)

#define STAGE_A(kt, BI) do {                                                  \
    __bf16* _dst = &As[(BI)][0];                                              \
    async_copy16(gA + (size_t)srow[0] * IN_F + (kt) * TK2 + slg[0] * 8,       \
                 _dst + t * 8);                                               \
    async_copy16(gA + (size_t)srow[1] * IN_F + (kt) * TK2 + slg[1] * 8,       \
                 _dst + (256 + t) * 8);                                       \
} while (0)

#define B_LOAD(kt) do {                                                       \
    const float* _p0 = gB0 + (kt) * TK2;                                      \
    const float* _p1 = gB1 + (kt) * TK2;                                      \
    Br[0] = *(const f32x4*)_p0;                                               \
    Br[1] = *(const f32x4*)(_p0 + 4);                                         \
    Br[2] = *(const f32x4*)_p1;                                               \
    Br[3] = *(const f32x4*)(_p1 + 4);                                         \
} while (0)

#define B_WRITE(BI) do {                                                      \
    __bf16* _d = &Bs[(BI)][0];                                                \
    bf16x8 _o;                                                                \
    _o[0] = (__bf16)Br[0][0]; _o[1] = (__bf16)Br[0][1];                       \
    _o[2] = (__bf16)Br[0][2]; _o[3] = (__bf16)Br[0][3];                       \
    _o[4] = (__bf16)Br[1][0]; _o[5] = (__bf16)Br[1][1];                       \
    _o[6] = (__bf16)Br[1][2]; _o[7] = (__bf16)Br[1][3];                       \
    *(bf16x8*)(_d + (size_t)t * 8) = _o;                                      \
    _o[0] = (__bf16)Br[2][0]; _o[1] = (__bf16)Br[2][1];                       \
    _o[2] = (__bf16)Br[2][2]; _o[3] = (__bf16)Br[2][3];                       \
    _o[4] = (__bf16)Br[3][0]; _o[5] = (__bf16)Br[3][1];                       \
    _o[6] = (__bf16)Br[3][2]; _o[7] = (__bf16)Br[3][3];                       \
    *(bf16x8*)(_d + (size_t)(256 + t) * 8) = _o;                              \
} while (0)

#define BARR()    do { __builtin_amdgcn_s_barrier();                          \
                       asm volatile("" ::: "memory"); } while (0)
#define LGKM0()   asm volatile("s_waitcnt lgkmcnt(0)" ::: "memory")
#define VMCNT(n)  asm volatile("s_waitcnt vmcnt(" #n ")" ::: "memory")

    // ---- prologue: stage tile 0 ----
    B_LOAD(0);                 // 4 loads
    STAGE_A(0, 0);             // 2 dmas
    VMCNT(2);                  // B landed (A dmas are the 2 youngest)
    B_WRITE(0);
    VMCNT(0);                  // A dma landed
    LGKM0();                   // own ds_writes visible
    BARR();

    // ONE barrier per K-tile. Invariant entering tile kt: buffer P=kt&1
    // holds tile kt; no vmem outstanding. Issue kt+1 staging first
    // (B->regs, A->DMA into QI), then 8 ds_read + 16 MFMA (compiler-
    // scheduled counted lgkm waits), then vmcnt(0)+B_WRITE+lgkm0+barrier.
    // WAR: QI's readers drained their reads before the previous barrier.
#define TILE_BODY(kt, P, QI) do {                                             \
    const char* _ab = (const char*)&As[(P)][0];                               \
    const char* _bb = (const char*)&Bs[(P)][0];                               \
    if ((kt) + 1 < NT2) {                                                     \
        B_LOAD((kt) + 1);                                                     \
        STAGE_A((kt) + 1, QI);                                                \
    }                                                                         \
    bf16x8 afr[4], bfr[4];                                                    \
    _Pragma("unroll")                                                         \
    for (int _mt = 0; _mt < 4; ++_mt)                                         \
        afr[_mt] = *(const bf16x8*)(_ab + aoff[_mt]);                         \
    _Pragma("unroll")                                                         \
    for (int _nt = 0; _nt < 4; ++_nt)                                         \
        bfr[_nt] = *(const bf16x8*)(_bb + boff[_nt]);                         \
    _Pragma("unroll")                                                         \
    for (int _mt = 0; _mt < 4; ++_mt)                                         \
        _Pragma("unroll")                                                     \
        for (int _nt = 0; _nt < 4; ++_nt)                                     \
            acc[_mt][_nt] = __builtin_amdgcn_mfma_f32_16x16x32_bf16(          \
                afr[_mt], bfr[_nt], acc[_mt][_nt], 0, 0, 0);                  \
    VMCNT(0);   /* staging issued a full tile ago */                          \
    if ((kt) + 1 < NT2) B_WRITE(QI);                                          \
    LGKM0();    /* own reads done (WAR) + own writes visible */               \
    BARR();                                                                   \
} while (0)

    for (int it = 0; it < NT2 / 2; ++it) {
        const int kte = 2 * it;
        TILE_BODY(kte,     0, 1);
        TILE_BODY(kte + 1, 1, 0);
    }

#undef TILE_BODY
#undef STAGE_A
#undef B_LOAD
#undef B_WRITE
#undef BARR
#undef LGKM0
#undef VMCNT

    // epilogue (R8's probe-verified C/D layout: n = lane&15, m = q*4 + reg)
    float bv[4];
    #pragma unroll
    for (int nt = 0; nt < 4; ++nt)
        bv[nt] = bias[n0 + wn * 64 + nt * 16 + lidx];

    if (f32w) {
        float* yf = (float*)yraw;
        #pragma unroll
        for (int mt = 0; mt < 4; ++mt)
            #pragma unroll
            for (int r = 0; r < 4; ++r) {
                const int m = m0 + wm * 64 + mt * 16 + q * 4 + r;
                float* yp = yf + (size_t)m * OUT_F + n0 + wn * 64 + lidx;
                #pragma unroll
                for (int nt = 0; nt < 4; ++nt)
                    yp[nt * 16] = acc[mt][nt][r] * scale + bv[nt];
            }
    } else {
        __bf16* yh = (__bf16*)yraw;
        #pragma unroll
        for (int mt = 0; mt < 4; ++mt)
            #pragma unroll
            for (int r = 0; r < 4; ++r) {
                const int m = m0 + wm * 64 + mt * 16 + q * 4 + r;
                __bf16* yp = yh + (size_t)m * OUT_F + n0 + wn * 64 + lidx;
                #pragma unroll
                for (int nt = 0; nt < 4; ++nt)
                    yp[nt * 16] = (__bf16)(acc[mt][nt][r] * scale + bv[nt]);
            }
    }
}

// ---- fallback (R6 kernel): only if ws_size can't hold cvt_x buffer ----
__global__ __launch_bounds__(256) void f8linear_fallback(
    const void*  __restrict__ xraw,
    const float* __restrict__ wq,
    const float* __restrict__ w_scale,
    const float* __restrict__ bias,
    void*        __restrict__ yraw,
    const int*   __restrict__ flag_p)
{
    __shared__ __align__(16) __bf16 As[BM * 40];
    __shared__ __align__(16) __bf16 Bs[BN * 40];

    const int f32w = (*flag_p != 0);
    const int t    = threadIdx.x;
    const int lane = t & 63;
    const int wv   = t >> 6;
    const int wm   = wv >> 1;
    const int wn   = wv & 1;
    const int lidx = lane & 15;
    const int q    = lane >> 4;

    const int flat = blockIdx.x;
    const int xcd  = flat & 7;
    const int slot = flat >> 3;
    const int ni   = xcd * 14 + (slot >> 3);
    const int mi   = slot & 7;
    const int m0   = mi * BM;
    const int n0   = ni * BN;

    const float scale = w_scale[0];
    const float*  xf = (const float*)xraw;
    const __bf16* xh = (const __bf16*)xraw;

    const int af_row = t >> 3;
    const int af_col = (t & 7) * 4;
    int ah_row[2], ah_cg[2];
    #pragma unroll
    for (int i = 0; i < 2; ++i) {
        const int s = i * 256 + t;
        ah_row[i] = s >> 2;
        ah_cg[i]  = s & 3;
    }
    const int b_row = t >> 3;
    const int b_col = (t & 7) * 4;

    const f32x4 zero4 = {0.f, 0.f, 0.f, 0.f};
    f32x4 acc[4][4];
    #pragma unroll
    for (int i = 0; i < 4; ++i)
        #pragma unroll
        for (int j = 0; j < 4; ++j)
            acc[i][j] = zero4;

    f32x4  aregf[4];
    bf16x8 aregh[2];
    f32x4  breg[4];
    if (f32w) {
        #pragma unroll
        for (int i = 0; i < 4; ++i)
            aregf[i] = *reinterpret_cast<const f32x4*>(
                xf + (size_t)(m0 + af_row + i * 32) * IN_F + af_col);
    } else {
        #pragma unroll
        for (int i = 0; i < 2; ++i)
            aregh[i] = *reinterpret_cast<const bf16x8*>(
                xh + (size_t)(m0 + ah_row[i]) * IN_F + ah_cg[i] * 8);
    }
    #pragma unroll
    for (int i = 0; i < 4; ++i)
        breg[i] = *reinterpret_cast<const f32x4*>(
            wq + (size_t)(n0 + i * 32 + b_row) * IN_F + b_col);

    for (int kt = 0; kt < 128; ++kt) {
        const int k0 = kt * 32;
        if (f32w) {
            #pragma unroll
            for (int i = 0; i < 4; ++i) {
                bf16x4 pk;
                pk[0] = (__bf16)aregf[i][0];
                pk[1] = (__bf16)aregf[i][1];
                pk[2] = (__bf16)aregf[i][2];
                pk[3] = (__bf16)aregf[i][3];
                *reinterpret_cast<bf16x4*>(As + (af_row + i * 32) * 40 + af_col) = pk;
            }
        } else {
            #pragma unroll
            for (int i = 0; i < 2; ++i)
                *reinterpret_cast<bf16x8*>(As + ah_row[i] * 40 + ah_cg[i] * 8) = aregh[i];
        }
        #pragma unroll
        for (int i = 0; i < 4; ++i) {
            bf16x4 pk;
            pk[0] = (__bf16)breg[i][0];
            pk[1] = (__bf16)breg[i][1];
            pk[2] = (__bf16)breg[i][2];
            pk[3] = (__bf16)breg[i][3];
            *reinterpret_cast<bf16x4*>(Bs + (i * 32 + b_row) * 40 + b_col) = pk;
        }
        __syncthreads();
        if (kt + 1 < 128) {
            const int k1 = k0 + 32;
            if (f32w) {
                #pragma unroll
                for (int i = 0; i < 4; ++i)
                    aregf[i] = *reinterpret_cast<const f32x4*>(
                        xf + (size_t)(m0 + af_row + i * 32) * IN_F + k1 + af_col);
            } else {
                #pragma unroll
                for (int i = 0; i < 2; ++i)
                    aregh[i] = *reinterpret_cast<const bf16x8*>(
                        xh + (size_t)(m0 + ah_row[i]) * IN_F + k1 + ah_cg[i] * 8);
            }
            #pragma unroll
            for (int i = 0; i < 4; ++i)
                breg[i] = *reinterpret_cast<const f32x4*>(
                    wq + (size_t)(n0 + i * 32 + b_row) * IN_F + k1 + b_col);
        }
        bf16x8 afr[4], bfr[4];
        #pragma unroll
        for (int mt = 0; mt < 4; ++mt) {
            const int row = wm * 64 + mt * 16 + lidx;
            afr[mt] = *reinterpret_cast<const bf16x8*>(As + row * 40 + q * 8);
        }
        #pragma unroll
        for (int nt = 0; nt < 4; ++nt) {
            const int row = wn * 64 + nt * 16 + lidx;
            bfr[nt] = *reinterpret_cast<const bf16x8*>(Bs + row * 40 + q * 8);
        }
        #pragma unroll
        for (int mt = 0; mt < 4; ++mt)
            #pragma unroll
            for (int nt = 0; nt < 4; ++nt)
                acc[mt][nt] = __builtin_amdgcn_mfma_f32_16x16x32_bf16(
                    afr[mt], bfr[nt], acc[mt][nt], 0, 0, 0);
        __syncthreads();
    }

    float bv[4];
    #pragma unroll
    for (int nt = 0; nt < 4; ++nt)
        bv[nt] = bias[n0 + wn * 64 + nt * 16 + lidx];

    if (f32w) {
        float* yf = (float*)yraw;
        #pragma unroll
        for (int mt = 0; mt < 4; ++mt)
            #pragma unroll
            for (int r = 0; r < 4; ++r) {
                const int m = m0 + wm * 64 + mt * 16 + q * 4 + r;
                float* yp = yf + (size_t)m * OUT_F + n0 + wn * 64 + lidx;
                #pragma unroll
                for (int nt = 0; nt < 4; ++nt)
                    yp[nt * 16] = acc[mt][nt][r] * scale + bv[nt];
            }
    } else {
        __bf16* yh = (__bf16*)yraw;
        #pragma unroll
        for (int mt = 0; mt < 4; ++mt)
            #pragma unroll
            for (int r = 0; r < 4; ++r) {
                const int m = m0 + wm * 64 + mt * 16 + q * 4 + r;
                __bf16* yp = yh + (size_t)m * OUT_F + n0 + wn * 64 + lidx;
                #pragma unroll
                for (int nt = 0; nt < 4; ++nt)
                    yp[nt * 16] = (__bf16)(acc[mt][nt][r] * scale + bv[nt]);
            }
    }
}

extern "C" void kernel_launch(void* const* d_in, const int* in_sizes, int n_in,
                              void* d_out, int out_size, void* d_ws, size_t ws_size,
                              hipStream_t stream) {
    const void* px = nullptr; const void* pw = nullptr;
    const void* ps = nullptr; const void* pb = nullptr;
    for (int i = 0; i < n_in; ++i) {
        const long sz = in_sizes[i];
        if      (sz == (long)M_TOT * IN_F) px = d_in[i];
        else if (sz == (long)OUT_F * IN_F) pw = d_in[i];
        else if (sz == 1)                  ps = d_in[i];
        else if (sz == OUT_F)              pb = d_in[i];
    }
    if (!px) px = d_in[0];
    if (!pw) pw = d_in[1];
    if (!ps) ps = d_in[2];
    if (!pb) pb = d_in[3];

    const size_t X_BYTES  = (size_t)M_TOT * IN_F * 2;   // 8,388,608
    const size_t FLAG_OFF = X_BYTES;

    if (ws_size >= FLAG_OFF + 16) {
        __bf16* xbf  = (__bf16*)d_ws;
        int*    flag = (int*)((char*)d_ws + FLAG_OFF);

        const int grid16 = (M_TOT / TM2) * (OUT_F / TN2);  // 896

        detect_x_dtype<<<1, 256, 0, stream>>>((const uint32_t*)px, flag);
        cvt_x_kernel<<<2048, 256, 0, stream>>>(px, (bf16x8*)xbf, flag);
        gemm_fused_occ<<<grid16, 256, 0, stream>>>(
            xbf, (const float*)pw, (const float*)ps, (const float*)pb,
            d_out, flag);
    } else {
        int* flag = (int*)d_ws;
        const int grid = (M_TOT / BM) * (OUT_F / BN);   // 896
        detect_x_dtype<<<1, 256, 0, stream>>>((const uint32_t*)px, flag);
        f8linear_fallback<<<grid, 256, 0, stream>>>(
            px, (const float*)pw, (const float*)ps, (const float*)pb, d_out, flag);
    }
}